// Round 4
// baseline (4979.473 us; speedup 1.0000x reference)
//
#include <hip/hip_runtime.h>
#include <math.h>

#pragma clang fp contract(off)

#define NROWS 131072

// selu matching np: scale * where(x>0, x, alpha*expm1(x)), each op rounded separately
__device__ __forceinline__ float selu_f(float v) {
    float em  = expm1f(v);
    float neg = 1.6732632423543772f * em;
    float r   = v > 0.0f ? v : neg;
    return 1.0507009873554805f * r;
}

__device__ __forceinline__ float4 ldf4(const float* p) { return *(const float4*)p; }

__device__ __forceinline__ void ld2x4(float4* b, const float* p) {
    b[0] = ldf4(p); b[1] = ldf4(p + 4);
}

__device__ __forceinline__ void fma8a(float* a, const float4* w, float h) {
    a[0] = __builtin_fmaf(w[0].x, h, a[0]); a[1] = __builtin_fmaf(w[0].y, h, a[1]);
    a[2] = __builtin_fmaf(w[0].z, h, a[2]); a[3] = __builtin_fmaf(w[0].w, h, a[3]);
    a[4] = __builtin_fmaf(w[1].x, h, a[4]); a[5] = __builtin_fmaf(w[1].y, h, a[5]);
    a[6] = __builtin_fmaf(w[1].z, h, a[6]); a[7] = __builtin_fmaf(w[1].w, h, a[7]);
}

// rotate step: issue next row's 2xf4 loads, consume current buffer, rotate in
__device__ __forceinline__ void step8(float* acc, float4* wb, const float* nextp, float h) {
    float4 t0 = ldf4(nextp), t1 = ldf4(nextp + 4);
    fma8a(acc, wb, h);
    wb[0] = t0; wb[1] = t1;
}

// ---------- prep 1: W2 [256,256] -> W2T [j][c]; W3 [64,256] -> W3T [c][e]; W1 [256,64] -> W1T [j][c]
__global__ void prep_transpose(const float* __restrict__ W1, const float* __restrict__ W2,
                               const float* __restrict__ W3,
                               float* __restrict__ W1T, float* __restrict__ W2T,
                               float* __restrict__ W3T) {
    int id = blockIdx.x * 256 + threadIdx.x;
    if (id < 65536) { int c = id >> 8, j = id & 255; W2T[j * 256 + c] = W2[id]; }
    int id2 = id - 65536;
    if (id2 >= 0 && id2 < 16384) { int e = id2 >> 8, c = id2 & 255; W3T[c * 64 + e] = W3[id2]; }
    int id3 = id - 81920;
    if (id3 >= 0 && id3 < 16384) { int c = id3 >> 6, j = id3 & 63; W1T[j * 256 + c] = W1[id3]; }
}

// ---------- prep 2: decoder table dec_out[k] = decoder(emb[k]), and en[k] = ||emb_k||^2 ----------
__global__ void prep_decoder(const float* __restrict__ emb,
                             const float* __restrict__ Wd1, const float* __restrict__ bd1,
                             const float* __restrict__ Wd2, const float* __restrict__ bd2,
                             const float* __restrict__ Wd3, const float* __restrict__ bd3,
                             float* __restrict__ dec_out, float* __restrict__ en) {
    __shared__ float e[64];
    __shared__ float h1[256];
    __shared__ float h2[256];
    const int t = threadIdx.x; // 256 threads
    for (int kc = 0; kc < 4; ++kc) {
        const int k = blockIdx.x * 4 + kc;
        __syncthreads();
        if (t < 64) e[t] = emb[k * 64 + t];
        __syncthreads();
        {
            float acc = 0.0f;
            const float* w = Wd1 + t * 64;
            #pragma unroll
            for (int j = 0; j < 64; ++j) acc = __builtin_fmaf(w[j], e[j], acc);
            h1[t] = selu_f(acc + bd1[t]);
        }
        __syncthreads();
        {
            float acc = 0.0f;
            const float* w = Wd2 + t * 256;
            #pragma unroll 8
            for (int j = 0; j < 256; ++j) acc = __builtin_fmaf(w[j], h1[j], acc);
            h2[t] = selu_f(acc + bd2[t]);
        }
        __syncthreads();
        if (t < 64) {
            float acc = 0.0f;
            const float* w = Wd3 + t * 256;
            #pragma unroll 8
            for (int j = 0; j < 256; ++j) acc = __builtin_fmaf(w[j], h2[j], acc);
            dec_out[k * 64 + t] = acc + bd3[t];
        }
        if (t == 0) {
            float r[8];
            #pragma unroll
            for (int u = 0; u < 8; ++u) r[u] = e[u] * e[u];
            #pragma unroll
            for (int i = 8; i < 64; i += 8) {
                #pragma unroll
                for (int u = 0; u < 8; ++u) { float p = e[i + u] * e[i + u]; r[u] = r[u] + p; }
            }
            en[k] = ((r[0] + r[1]) + (r[2] + r[3])) + ((r[4] + r[5]) + (r[6] + r[7]));
        }
    }
}

// ---------- main kernel ----------
// block = 512 threads = 8 waves, 64 rows (lane = row). Wave w owns 8-col slices / 8-e-range / 128-code slice.
// LDS: R1[16384] = h1 (j-pair layout) -> zs (stride 68); aux[4096] = xT -> h2 staging -> cand/ix.
// 2 blocks/CU (160 KiB LDS) = 4 waves/SIMD; weights stream from L2 via laundered VMEM + depth-4 rotate.
__global__ __launch_bounds__(512, 4)
void vqvae_main(const float* __restrict__ x,
                const float* __restrict__ b1, const float* __restrict__ b2,
                const float* __restrict__ b3,
                const float* __restrict__ W1T, const float* __restrict__ W2T,
                const float* __restrict__ W3T,
                const float* __restrict__ emb, const float* __restrict__ en,
                const float* __restrict__ dec_out, float* __restrict__ out) {
    __shared__ __align__(16) float R1[16384];
    __shared__ __align__(16) float aux[4096];

    const int t    = threadIdx.x;
    const int wave = t >> 6;            // 0..7
    const int lane = t & 63;            // row
    const size_t rowbase = (size_t)blockIdx.x * 64;

    // opaque zero in a VGPR: keeps uniform loads on the vector pipe (vmcnt, pipelinable)
    int lz;
    asm volatile("v_mov_b32 %0, 0" : "=v"(lz));

    const float* W1Tv = W1T + lz;
    const float* W2Tv = W2T + lz;
    const float* W3Tv = W3T + lz;
    const float* b1v  = b1 + lz;
    const float* b2v  = b2 + lz;
    const float* b3v  = b3 + lz;
    const float* env  = en + lz;
    const float* embv = emb + lz;

    // ---- phase 0: stage x tile transposed into aux: xT[j][r]
    #pragma unroll
    for (int q = 0; q < 2; ++q) {
        int f = t + 512 * q;
        int r = f >> 4, c4 = f & 15;
        float4 v = ldf4(x + (rowbase + r) * 64 + c4 * 4);
        aux[(c4 * 4 + 0) * 64 + r] = v.x;
        aux[(c4 * 4 + 1) * 64 + r] = v.y;
        aux[(c4 * 4 + 2) * 64 + r] = v.z;
        aux[(c4 * 4 + 3) * 64 + r] = v.w;
    }
    __syncthreads();

    // ---- phase 1: layer1. group g: wave computes cols cg=64g+8*wave .. +8.
    // h1 stored as j-pairs: R1[(c>>1)*128 + lane*2 + (c&1)]
    for (int g = 0; g < 4; ++g) {
        const int cg = g * 64 + wave * 8;
        const float* wp = W1Tv + cg;      // row j at wp + j*256
        float4 A0[2], A1[2], A2[2], A3[2];
        ld2x4(A0, wp); ld2x4(A1, wp + 256); ld2x4(A2, wp + 512); ld2x4(A3, wp + 768);
        float acc[8];
        #pragma unroll
        for (int u = 0; u < 8; ++u) acc[u] = 0.0f;
        #pragma unroll 1
        for (int j = 0; j < 64; j += 4) {
            const float* np = wp + (j + 4) * 256;   // rows 64..67 overrun into W3T region (in-ws)
            step8(acc, A0, np,        aux[(j + 0) * 64 + lane]);
            step8(acc, A1, np + 256,  aux[(j + 1) * 64 + lane]);
            step8(acc, A2, np + 512,  aux[(j + 2) * 64 + lane]);
            step8(acc, A3, np + 768,  aux[(j + 3) * 64 + lane]);
        }
        float bb[8];
        *(float4*)&bb[0] = ldf4(b1v + cg);
        *(float4*)&bb[4] = ldf4(b1v + cg + 4);
        float hv[8];
        #pragma unroll
        for (int u = 0; u < 8; ++u) hv[u] = selu_f(acc[u] + bb[u]);
        #pragma unroll
        for (int up = 0; up < 4; ++up) {
            *(float2*)&R1[((cg >> 1) + up) * 128 + (lane << 1)] = make_float2(hv[2 * up], hv[2 * up + 1]);
        }
    }
    __syncthreads();

    // ---- phase 2: layer2 + layer3, group-staged.
    // group g = col-block [64g, 64g+64): wave computes 8 cols, stages h2 in aux,
    // then folds the 64-col block into its e-range er=[8*wave, +8) -> partial P_g.
    // z = ((P0+P1)+(P2+P3)) + b3  (identical chain to passing rounds)
    const int er = wave * 8;
    float s01[8], s23[8];
    for (int g = 0; g < 4; ++g) {
        const int cg = g * 64 + wave * 8;
        const float* wp = W2Tv + cg;      // row j at wp + j*256
        float4 A0[2], A1[2], A2[2], A3[2];
        ld2x4(A0, wp); ld2x4(A1, wp + 256); ld2x4(A2, wp + 512); ld2x4(A3, wp + 768);
        float acc[8];
        #pragma unroll
        for (int u = 0; u < 8; ++u) acc[u] = 0.0f;
        #pragma unroll 1
        for (int j = 0; j < 256; j += 4) {
            const float* np = wp + (j + 4) * 256; // rows 256..259 land in W1T region (in-ws)
            float2 h01 = *(const float2*)&R1[(j >> 1) * 128 + (lane << 1)];
            step8(acc, A0, np,        h01.x);
            step8(acc, A1, np + 256,  h01.y);
            float2 h23 = *(const float2*)&R1[((j >> 1) + 1) * 128 + (lane << 1)];
            step8(acc, A2, np + 512,  h23.x);
            step8(acc, A3, np + 768,  h23.y);
        }
        __syncthreads();   // previous fold's readers of aux are done
        {
            float bb[8];
            *(float4*)&bb[0] = ldf4(b2v + cg);
            *(float4*)&bb[4] = ldf4(b2v + cg + 4);
            #pragma unroll
            for (int u = 0; u < 8; ++u)
                aux[(wave * 8 + u) * 64 + lane] = selu_f(acc[u] + bb[u]);
        }
        __syncthreads();   // h2 of this col-block visible
        // fold col-block g (cols 64g..64g+63 ascending) into e-range er..er+8
        const float* w3p = W3Tv + g * 4096 + er;    // col (64g+c) at w3p + c*64
        float4 F0[2], F1[2], F2[2], F3[2];
        ld2x4(F0, w3p); ld2x4(F1, w3p + 64); ld2x4(F2, w3p + 128); ld2x4(F3, w3p + 192);
        float P[8];
        #pragma unroll
        for (int u = 0; u < 8; ++u) P[u] = 0.0f;
        #pragma unroll 1
        for (int c = 0; c < 64; c += 4) {
            const float* np = w3p + (c + 4) * 64;  // overrun into en pad (in-ws)
            step8(P, F0, np,        aux[(c + 0) * 64 + lane]);
            step8(P, F1, np + 64,   aux[(c + 1) * 64 + lane]);
            step8(P, F2, np + 128,  aux[(c + 2) * 64 + lane]);
            step8(P, F3, np + 192,  aux[(c + 3) * 64 + lane]);
        }
        if (g == 0) {
            #pragma unroll
            for (int u = 0; u < 8; ++u) s01[u] = P[u];
        } else if (g == 1) {
            #pragma unroll
            for (int u = 0; u < 8; ++u) s01[u] = s01[u] + P[u];
        } else if (g == 2) {
            #pragma unroll
            for (int u = 0; u < 8; ++u) s23[u] = P[u];
        } else {
            #pragma unroll
            for (int u = 0; u < 8; ++u) s23[u] = s23[u] + P[u];
        }
    }

    // ---- phase 3: z = (s01+s23)+b3; park z in LDS (zs[lane][e], stride 68)
    {
        float bb[8];
        *(float4*)&bb[0] = ldf4(b3v + er);
        *(float4*)&bb[4] = ldf4(b3v + er + 4);
        float zv[8];
        #pragma unroll
        for (int u = 0; u < 8; ++u) zv[u] = (s01[u] + s23[u]) + bb[u];
        *(float4*)&R1[lane * 68 + er]     = make_float4(zv[0], zv[1], zv[2], zv[3]);
        *(float4*)&R1[lane * 68 + er + 4] = make_float4(zv[4], zv[5], zv[6], zv[7]);
    }
    __syncthreads();

    // A = ||z||^2 with numpy pairwise chain (8 strided accumulators, balanced tree)
    float A;
    {
        float z[64];
        #pragma unroll
        for (int m = 0; m < 16; ++m) {
            float4 v = *(const float4*)&R1[lane * 68 + m * 4];
            z[4 * m] = v.x; z[4 * m + 1] = v.y; z[4 * m + 2] = v.z; z[4 * m + 3] = v.w;
        }
        float r[8];
        #pragma unroll
        for (int u = 0; u < 8; ++u) r[u] = z[u] * z[u];
        #pragma unroll
        for (int i = 8; i < 64; i += 8) {
            #pragma unroll
            for (int u = 0; u < 8; ++u) { float p = z[i + u] * z[i + u]; r[u] = r[u] + p; }
        }
        A = ((r[0] + r[1]) + (r[2] + r[3])) + ((r[4] + r[5]) + (r[6] + r[7]));
    }

    // ---- phase 4: scores over wave's 128-code slice, 8-code chunks, z quarters re-read from LDS
    float best = 3.4e38f;
    const int k0 = wave * 128;
    int bk = k0;
    const float* embw = embv + (size_t)k0 * 64;
    #pragma unroll 1
    for (int kc = 0; kc < 128; kc += 8) {
        float4 en03 = ldf4(env + k0 + kc);
        float4 en47 = ldf4(env + k0 + kc + 4);
        float d0[8], d1[8], d2[8], d3[8];
        #pragma unroll
        for (int c = 0; c < 8; ++c) { d0[c] = 0.f; d1[c] = 0.f; d2[c] = 0.f; d3[c] = 0.f; }
        #pragma unroll
        for (int q = 0; q < 4; ++q) {
            float4 zq0 = *(const float4*)&R1[lane * 68 + q * 16];
            float4 zq1 = *(const float4*)&R1[lane * 68 + q * 16 + 4];
            float4 zq2 = *(const float4*)&R1[lane * 68 + q * 16 + 8];
            float4 zq3 = *(const float4*)&R1[lane * 68 + q * 16 + 12];
            #pragma unroll
            for (int c = 0; c < 8; ++c) {
                const float* ep = embw + (kc + c) * 64 + q * 16;
                float4 e0 = ldf4(ep), e1 = ldf4(ep + 4), e2 = ldf4(ep + 8), e3 = ldf4(ep + 12);
                d0[c] = __builtin_fmaf(zq0.x, e0.x, d0[c]);
                d1[c] = __builtin_fmaf(zq0.y, e0.y, d1[c]);
                d2[c] = __builtin_fmaf(zq0.z, e0.z, d2[c]);
                d3[c] = __builtin_fmaf(zq0.w, e0.w, d3[c]);
                d0[c] = __builtin_fmaf(zq1.x, e1.x, d0[c]);
                d1[c] = __builtin_fmaf(zq1.y, e1.y, d1[c]);
                d2[c] = __builtin_fmaf(zq1.z, e1.z, d2[c]);
                d3[c] = __builtin_fmaf(zq1.w, e1.w, d3[c]);
                d0[c] = __builtin_fmaf(zq2.x, e2.x, d0[c]);
                d1[c] = __builtin_fmaf(zq2.y, e2.y, d1[c]);
                d2[c] = __builtin_fmaf(zq2.z, e2.z, d2[c]);
                d3[c] = __builtin_fmaf(zq2.w, e2.w, d3[c]);
                d0[c] = __builtin_fmaf(zq3.x, e3.x, d0[c]);
                d1[c] = __builtin_fmaf(zq3.y, e3.y, d1[c]);
                d2[c] = __builtin_fmaf(zq3.z, e3.z, d2[c]);
                d3[c] = __builtin_fmaf(zq3.w, e3.w, d3[c]);
            }
        }
        float enb[8];
        *(float4*)&enb[0] = en03; *(float4*)&enb[4] = en47;
        #pragma unroll
        for (int c = 0; c < 8; ++c) {
            float dot = (d0[c] + d1[c]) + (d2[c] + d3[c]);
            float tt  = __builtin_fmaf(-2.0f, dot, A);
            float s   = tt + enb[c];
            if (s < best) { best = s; bk = k0 + kc + c; }
        }
    }

    // ---- phase 5: cross-wave argmin (ascending wave => first-min); aux dead -> cand storage
    float* cand_s = aux + 64;                 // 512 floats
    int*   cand_k = ((int*)aux) + 576;        // 512 ints
    int*   ixp    = (int*)aux;                // 64 ints
    cand_s[wave * 64 + lane] = best;
    cand_k[wave * 64 + lane] = bk;
    __syncthreads();
    if (t < 64) {
        float s0 = cand_s[t];
        int   kk = cand_k[t];
        #pragma unroll
        for (int w2 = 1; w2 < 8; ++w2) {
            float sw = cand_s[w2 * 64 + t];
            if (sw < s0) { s0 = sw; kk = cand_k[w2 * 64 + t]; }
        }
        ixp[t] = kk;
        out[(size_t)NROWS * 64 + rowbase + t] = (float)kk;
    }
    __syncthreads();

    // ---- phase 6: recon = dec_out[idx], coalesced f4 store
    #pragma unroll
    for (int q = 0; q < 2; ++q) {
        int f = t + 512 * q;
        int r = f >> 4, c4 = f & 15;
        float4 v = ldf4(dec_out + (size_t)ixp[r] * 64 + c4 * 4);
        *(float4*)(out + (rowbase + r) * 64 + c4 * 4) = v;
    }
}

extern "C" void kernel_launch(void* const* d_in, const int* in_sizes, int n_in,
                              void* d_out, int out_size, void* d_ws, size_t ws_size,
                              hipStream_t stream) {
    const float* x   = (const float*)d_in[0];
    const float* We1 = (const float*)d_in[1];
    const float* be1 = (const float*)d_in[2];
    const float* We2 = (const float*)d_in[3];
    const float* be2 = (const float*)d_in[4];
    const float* We3 = (const float*)d_in[5];
    const float* be3 = (const float*)d_in[6];
    const float* emb = (const float*)d_in[7];
    const float* Wd1 = (const float*)d_in[8];
    const float* bd1 = (const float*)d_in[9];
    const float* Wd2 = (const float*)d_in[10];
    const float* bd2 = (const float*)d_in[11];
    const float* Wd3 = (const float*)d_in[12];
    const float* bd3 = (const float*)d_in[13];
    float* out = (float*)d_out;

    // ws layout (floats): dec_out[65536] | W2T[65536] | W1T[16384] | W3T[16384] | en[1024+pad]
    float* ws      = (float*)d_ws;
    float* dec_out = ws;
    float* W2T     = ws + 65536;
    float* W1T     = ws + 131072;
    float* W3T     = ws + 147456;
    float* en      = ws + 163840;   // + pad absorbs fold prefetch overrun

    prep_transpose<<<384, 256, 0, stream>>>(We1, We2, We3, W1T, W2T, W3T);
    prep_decoder<<<256, 256, 0, stream>>>(emb, Wd1, bd1, Wd2, bd2, Wd3, bd3, dec_out, en);
    vqvae_main<<<NROWS / 64, 512, 0, stream>>>(x, be1, be2, be3, W1T, W2T, W3T, emb, en,
                                               dec_out, out);
}

// Round 5
// 2570.124 us; speedup vs baseline: 1.9374x; 1.9374x over previous
//
#include <hip/hip_runtime.h>
#include <math.h>

#pragma clang fp contract(off)

#define NROWS 131072

// selu matching np: scale * where(x>0, x, alpha*expm1(x)), each op rounded separately
__device__ __forceinline__ float selu_f(float v) {
    float em  = expm1f(v);
    float neg = 1.6732632423543772f * em;
    float r   = v > 0.0f ? v : neg;
    return 1.0507009873554805f * r;
}

__device__ __forceinline__ float4 ldf4(const float* p) { return *(const float4*)p; }

__device__ __forceinline__ void ld2x4(float4* b, const float* p) {
    b[0] = ldf4(p); b[1] = ldf4(p + 4);
}

__device__ __forceinline__ void fma8a(float* a, const float4* w, float h) {
    a[0] = __builtin_fmaf(w[0].x, h, a[0]); a[1] = __builtin_fmaf(w[0].y, h, a[1]);
    a[2] = __builtin_fmaf(w[0].z, h, a[2]); a[3] = __builtin_fmaf(w[0].w, h, a[3]);
    a[4] = __builtin_fmaf(w[1].x, h, a[4]); a[5] = __builtin_fmaf(w[1].y, h, a[5]);
    a[6] = __builtin_fmaf(w[1].z, h, a[6]); a[7] = __builtin_fmaf(w[1].w, h, a[7]);
}

// rotate step: issue next row's 2xf4 loads, consume current buffer, rotate in
__device__ __forceinline__ void step8(float* acc, float4* wb, const float* nextp, float h) {
    float4 t0 = ldf4(nextp), t1 = ldf4(nextp + 4);
    fma8a(acc, wb, h);
    wb[0] = t0; wb[1] = t1;
}

// ---------- prep 1: W2 [256,256] -> W2T [j][c]; W3 [64,256] -> W3T [c][e]; W1 [256,64] -> W1T [j][c]
__global__ void prep_transpose(const float* __restrict__ W1, const float* __restrict__ W2,
                               const float* __restrict__ W3,
                               float* __restrict__ W1T, float* __restrict__ W2T,
                               float* __restrict__ W3T) {
    int id = blockIdx.x * 256 + threadIdx.x;
    if (id < 65536) { int c = id >> 8, j = id & 255; W2T[j * 256 + c] = W2[id]; }
    int id2 = id - 65536;
    if (id2 >= 0 && id2 < 16384) { int e = id2 >> 8, c = id2 & 255; W3T[c * 64 + e] = W3[id2]; }
    int id3 = id - 81920;
    if (id3 >= 0 && id3 < 16384) { int c = id3 >> 6, j = id3 & 63; W1T[j * 256 + c] = W1[id3]; }
}

// ---------- prep 2: decoder table dec_out[k] = decoder(emb[k]), and en[k] = ||emb_k||^2 ----------
__global__ void prep_decoder(const float* __restrict__ emb,
                             const float* __restrict__ Wd1, const float* __restrict__ bd1,
                             const float* __restrict__ Wd2, const float* __restrict__ bd2,
                             const float* __restrict__ Wd3, const float* __restrict__ bd3,
                             float* __restrict__ dec_out, float* __restrict__ en) {
    __shared__ float e[64];
    __shared__ float h1[256];
    __shared__ float h2[256];
    const int t = threadIdx.x; // 256 threads
    for (int kc = 0; kc < 4; ++kc) {
        const int k = blockIdx.x * 4 + kc;
        __syncthreads();
        if (t < 64) e[t] = emb[k * 64 + t];
        __syncthreads();
        {
            float acc = 0.0f;
            const float* w = Wd1 + t * 64;
            #pragma unroll
            for (int j = 0; j < 64; ++j) acc = __builtin_fmaf(w[j], e[j], acc);
            h1[t] = selu_f(acc + bd1[t]);
        }
        __syncthreads();
        {
            float acc = 0.0f;
            const float* w = Wd2 + t * 256;
            #pragma unroll 8
            for (int j = 0; j < 256; ++j) acc = __builtin_fmaf(w[j], h1[j], acc);
            h2[t] = selu_f(acc + bd2[t]);
        }
        __syncthreads();
        if (t < 64) {
            float acc = 0.0f;
            const float* w = Wd3 + t * 256;
            #pragma unroll 8
            for (int j = 0; j < 256; ++j) acc = __builtin_fmaf(w[j], h2[j], acc);
            dec_out[k * 64 + t] = acc + bd3[t];
        }
        if (t == 0) {
            float r[8];
            #pragma unroll
            for (int u = 0; u < 8; ++u) r[u] = e[u] * e[u];
            #pragma unroll
            for (int i = 8; i < 64; i += 8) {
                #pragma unroll
                for (int u = 0; u < 8; ++u) { float p = e[i + u] * e[i + u]; r[u] = r[u] + p; }
            }
            en[k] = ((r[0] + r[1]) + (r[2] + r[3])) + ((r[4] + r[5]) + (r[6] + r[7]));
        }
    }
}

// ---------- main kernel ----------
// block = 256 threads = 4 waves, 32 rows. lane = (half,row): row = lane&31, half = lane>>5.
// slot = wave*2+half (0..7) owns 8-col slices per group / e-range [8*slot,+8) / 128-code slice.
// LDS 40 KB total -> 4 blocks/CU = 4 waves/SIMD (VGPR cap 128 via launch_bounds(256,4)).
// Weights stream from L2 via laundered VMEM + depth-4 register rotate (proven codegen shape).
__global__ __launch_bounds__(256, 4)
void vqvae_main(const float* __restrict__ x,
                const float* __restrict__ b1, const float* __restrict__ b2,
                const float* __restrict__ b3,
                const float* __restrict__ W1T, const float* __restrict__ W2T,
                const float* __restrict__ W3T,
                const float* __restrict__ emb, const float* __restrict__ en,
                const float* __restrict__ dec_out, float* __restrict__ out) {
    __shared__ __align__(16) float R1[8192];   // h1 (j-pair layout, 32 KB) -> zs (stride 67)
    __shared__ __align__(16) float aux[2048];  // xT -> h2 staging -> cand/ix (8 KB)

    const int t    = threadIdx.x;
    const int wave = t >> 6;            // 0..3
    const int lane = t & 63;
    const int row  = lane & 31;
    const int half = lane >> 5;         // 0..1
    const int slot = wave * 2 + half;   // 0..7 (ascending k-order for first-min)
    const size_t rowbase = (size_t)blockIdx.x * 32;

    // opaque zero in a VGPR: keeps uniform loads on the vector pipe (vmcnt, pipelinable)
    int lz;
    asm volatile("v_mov_b32 %0, 0" : "=v"(lz));

    const float* W1Tv = W1T + lz;
    const float* W2Tv = W2T + lz;
    const float* W3Tv = W3T + lz;
    const float* b1v  = b1 + lz;
    const float* b2v  = b2 + lz;
    const float* b3v  = b3 + lz;
    const float* env  = en + lz;
    const float* embv = emb + lz;

    // ---- phase 0: stage x tile transposed into aux: xT[j][row], j=0..63, row=0..31
    #pragma unroll
    for (int q = 0; q < 2; ++q) {
        int f = t + 256 * q;            // 0..511 float4s
        int r = f >> 4, c4 = f & 15;
        float4 v = ldf4(x + (rowbase + r) * 64 + c4 * 4);
        aux[(c4 * 4 + 0) * 32 + r] = v.x;
        aux[(c4 * 4 + 1) * 32 + r] = v.y;
        aux[(c4 * 4 + 2) * 32 + r] = v.z;
        aux[(c4 * 4 + 3) * 32 + r] = v.w;
    }
    __syncthreads();

    // ---- phase 1: layer1. group g: slot computes cols cg = 64g + 16*wave + 8*half .. +8.
    // h1 stored j-paired: word ((c>>1)*64 + row*2 + (c&1))
    for (int g = 0; g < 4; ++g) {
        const int cg = g * 64 + wave * 16 + half * 8;
        const float* wp = W1Tv + cg;      // row j at wp + j*256
        float4 A0[2], A1[2], A2[2], A3[2];
        ld2x4(A0, wp); ld2x4(A1, wp + 256); ld2x4(A2, wp + 512); ld2x4(A3, wp + 768);
        float acc[8];
        #pragma unroll
        for (int u = 0; u < 8; ++u) acc[u] = 0.0f;
        #pragma unroll 1
        for (int j = 0; j < 64; j += 4) {
            const float* np2 = wp + (j + 4) * 256;  // rows 64..67 overrun into W3T region (in-ws)
            step8(acc, A0, np2,        aux[(j + 0) * 32 + row]);
            step8(acc, A1, np2 + 256,  aux[(j + 1) * 32 + row]);
            step8(acc, A2, np2 + 512,  aux[(j + 2) * 32 + row]);
            step8(acc, A3, np2 + 768,  aux[(j + 3) * 32 + row]);
        }
        float bb[8];
        *(float4*)&bb[0] = ldf4(b1v + cg);
        *(float4*)&bb[4] = ldf4(b1v + cg + 4);
        float hv[8];
        #pragma unroll
        for (int u = 0; u < 8; ++u) hv[u] = selu_f(acc[u] + bb[u]);
        #pragma unroll
        for (int up = 0; up < 4; ++up) {
            *(float2*)&R1[((cg >> 1) + up) * 64 + (row << 1)] = make_float2(hv[2 * up], hv[2 * up + 1]);
        }
    }
    __syncthreads();

    // ---- phase 2: layer2 + layer3, group-staged.
    // group g: slot computes its 8 cols of col-block [64g,64g+64), stages h2 in aux,
    // then folds the 64-col block into e-range er=[8*slot,+8) -> partial P_g.
    // z = ((P0+P1)+(P2+P3)) + b3 (identical chain to passing rounds)
    const int er = slot * 8;
    float s01[8], s23[8];
    for (int g = 0; g < 4; ++g) {
        const int cg = g * 64 + wave * 16 + half * 8;
        const float* wp = W2Tv + cg;      // row j at wp + j*256
        float4 A0[2], A1[2], A2[2], A3[2];
        ld2x4(A0, wp); ld2x4(A1, wp + 256); ld2x4(A2, wp + 512); ld2x4(A3, wp + 768);
        float acc[8];
        #pragma unroll
        for (int u = 0; u < 8; ++u) acc[u] = 0.0f;
        #pragma unroll 1
        for (int j = 0; j < 256; j += 4) {
            const float* np2 = wp + (j + 4) * 256; // rows 256..259 land in W1T region (in-ws)
            float2 h01 = *(const float2*)&R1[(j >> 1) * 64 + (row << 1)];
            step8(acc, A0, np2,        h01.x);
            step8(acc, A1, np2 + 256,  h01.y);
            float2 h23 = *(const float2*)&R1[((j >> 1) + 1) * 64 + (row << 1)];
            step8(acc, A2, np2 + 512,  h23.x);
            step8(acc, A3, np2 + 768,  h23.y);
        }
        __syncthreads();   // previous fold's readers of aux are done (xT dead after phase 1)
        {
            float bb[8];
            *(float4*)&bb[0] = ldf4(b2v + cg);
            *(float4*)&bb[4] = ldf4(b2v + cg + 4);
            #pragma unroll
            for (int u = 0; u < 8; ++u)
                aux[(wave * 16 + half * 8 + u) * 32 + row] = selu_f(acc[u] + bb[u]);
        }
        __syncthreads();   // h2 of this col-block visible
        // fold col-block g (cols 64g..64g+63 ascending) into e-range er..er+8
        const float* w3p = W3Tv + g * 4096 + er;    // col (64g+c) at w3p + c*64
        float4 F0[2], F1[2], F2[2], F3[2];
        ld2x4(F0, w3p); ld2x4(F1, w3p + 64); ld2x4(F2, w3p + 128); ld2x4(F3, w3p + 192);
        float P[8];
        #pragma unroll
        for (int u = 0; u < 8; ++u) P[u] = 0.0f;
        #pragma unroll 1
        for (int c = 0; c < 64; c += 4) {
            const float* np2 = w3p + (c + 4) * 64;  // g=3 overrun into en region (in-ws)
            step8(P, F0, np2,        aux[(c + 0) * 32 + row]);
            step8(P, F1, np2 + 64,   aux[(c + 1) * 32 + row]);
            step8(P, F2, np2 + 128,  aux[(c + 2) * 32 + row]);
            step8(P, F3, np2 + 192,  aux[(c + 3) * 32 + row]);
        }
        if (g == 0) {
            #pragma unroll
            for (int u = 0; u < 8; ++u) s01[u] = P[u];
        } else if (g == 1) {
            #pragma unroll
            for (int u = 0; u < 8; ++u) s01[u] = s01[u] + P[u];
        } else if (g == 2) {
            #pragma unroll
            for (int u = 0; u < 8; ++u) s23[u] = P[u];
        } else {
            #pragma unroll
            for (int u = 0; u < 8; ++u) s23[u] = s23[u] + P[u];
        }
    }

    // ---- phase 3: z = (s01+s23)+b3; park z in R1 (zs[row][e], stride 67: 3r mod 32 bijective)
    // (all h1 reads are done: every wave passed g=3's barriers before its fold)
    {
        float bb[8];
        *(float4*)&bb[0] = ldf4(b3v + er);
        *(float4*)&bb[4] = ldf4(b3v + er + 4);
        float zv[8];
        #pragma unroll
        for (int u = 0; u < 8; ++u) zv[u] = (s01[u] + s23[u]) + bb[u];
        *(float4*)&R1[row * 67 + er]     = make_float4(zv[0], zv[1], zv[2], zv[3]);
        *(float4*)&R1[row * 67 + er + 4] = make_float4(zv[4], zv[5], zv[6], zv[7]);
    }
    __syncthreads();

    // A = ||z||^2 with numpy pairwise chain (8 strided accumulators, balanced tree)
    float A;
    {
        float z[64];
        #pragma unroll
        for (int m = 0; m < 16; ++m) {
            float4 v = *(const float4*)&R1[row * 67 + m * 4];
            z[4 * m] = v.x; z[4 * m + 1] = v.y; z[4 * m + 2] = v.z; z[4 * m + 3] = v.w;
        }
        float r[8];
        #pragma unroll
        for (int u = 0; u < 8; ++u) r[u] = z[u] * z[u];
        #pragma unroll
        for (int i = 8; i < 64; i += 8) {
            #pragma unroll
            for (int u = 0; u < 8; ++u) { float p = z[i + u] * z[i + u]; r[u] = r[u] + p; }
        }
        A = ((r[0] + r[1]) + (r[2] + r[3])) + ((r[4] + r[5]) + (r[6] + r[7]));
    }

    // ---- phase 4: scores over slot's 128-code slice, 8-code chunks, z quarters re-read from LDS
    float best = 3.4e38f;
    const int k0 = slot * 128;
    int bk = k0;
    const float* embw = embv + (size_t)k0 * 64;
    #pragma unroll 1
    for (int kc = 0; kc < 128; kc += 8) {
        float4 en03 = ldf4(env + k0 + kc);
        float4 en47 = ldf4(env + k0 + kc + 4);
        float d0[8], d1[8], d2[8], d3[8];
        #pragma unroll
        for (int c = 0; c < 8; ++c) { d0[c] = 0.f; d1[c] = 0.f; d2[c] = 0.f; d3[c] = 0.f; }
        #pragma unroll
        for (int q = 0; q < 4; ++q) {
            float4 zq0 = *(const float4*)&R1[row * 67 + q * 16];
            float4 zq1 = *(const float4*)&R1[row * 67 + q * 16 + 4];
            float4 zq2 = *(const float4*)&R1[row * 67 + q * 16 + 8];
            float4 zq3 = *(const float4*)&R1[row * 67 + q * 16 + 12];
            #pragma unroll
            for (int c = 0; c < 8; ++c) {
                const float* ep = embw + (kc + c) * 64 + q * 16;
                float4 e0 = ldf4(ep), e1 = ldf4(ep + 4), e2 = ldf4(ep + 8), e3 = ldf4(ep + 12);
                d0[c] = __builtin_fmaf(zq0.x, e0.x, d0[c]);
                d1[c] = __builtin_fmaf(zq0.y, e0.y, d1[c]);
                d2[c] = __builtin_fmaf(zq0.z, e0.z, d2[c]);
                d3[c] = __builtin_fmaf(zq0.w, e0.w, d3[c]);
                d0[c] = __builtin_fmaf(zq1.x, e1.x, d0[c]);
                d1[c] = __builtin_fmaf(zq1.y, e1.y, d1[c]);
                d2[c] = __builtin_fmaf(zq1.z, e1.z, d2[c]);
                d3[c] = __builtin_fmaf(zq1.w, e1.w, d3[c]);
                d0[c] = __builtin_fmaf(zq2.x, e2.x, d0[c]);
                d1[c] = __builtin_fmaf(zq2.y, e2.y, d1[c]);
                d2[c] = __builtin_fmaf(zq2.z, e2.z, d2[c]);
                d3[c] = __builtin_fmaf(zq2.w, e2.w, d3[c]);
                d0[c] = __builtin_fmaf(zq3.x, e3.x, d0[c]);
                d1[c] = __builtin_fmaf(zq3.y, e3.y, d1[c]);
                d2[c] = __builtin_fmaf(zq3.z, e3.z, d2[c]);
                d3[c] = __builtin_fmaf(zq3.w, e3.w, d3[c]);
            }
        }
        float enb[8];
        *(float4*)&enb[0] = en03; *(float4*)&enb[4] = en47;
        #pragma unroll
        for (int c = 0; c < 8; ++c) {
            float dot = (d0[c] + d1[c]) + (d2[c] + d3[c]);
            float tt  = __builtin_fmaf(-2.0f, dot, A);
            float s   = tt + enb[c];
            if (s < best) { best = s; bk = k0 + kc + c; }
        }
    }

    // ---- phase 5: cross-slot argmin (ascending slot = ascending k => first-min)
    float* cand_s = aux;                  // 256 floats
    int*   cand_k = ((int*)aux) + 256;    // 256 ints
    int*   ixp    = ((int*)aux) + 512;    // 32 ints
    cand_s[slot * 32 + row] = best;
    cand_k[slot * 32 + row] = bk;
    __syncthreads();
    if (t < 32) {
        float s0 = cand_s[t];
        int   kk = cand_k[t];
        #pragma unroll
        for (int w2 = 1; w2 < 8; ++w2) {
            float sw = cand_s[w2 * 32 + t];
            if (sw < s0) { s0 = sw; kk = cand_k[w2 * 32 + t]; }
        }
        ixp[t] = kk;
        out[(size_t)NROWS * 64 + rowbase + t] = (float)kk;
    }
    __syncthreads();

    // ---- phase 6: recon = dec_out[idx], coalesced f4 store
    #pragma unroll
    for (int q = 0; q < 2; ++q) {
        int f = t + 256 * q;
        int r = f >> 4, c4 = f & 15;
        float4 v = ldf4(dec_out + (size_t)ixp[r] * 64 + c4 * 4);
        *(float4*)(out + (rowbase + r) * 64 + c4 * 4) = v;
    }
}

extern "C" void kernel_launch(void* const* d_in, const int* in_sizes, int n_in,
                              void* d_out, int out_size, void* d_ws, size_t ws_size,
                              hipStream_t stream) {
    const float* x   = (const float*)d_in[0];
    const float* We1 = (const float*)d_in[1];
    const float* be1 = (const float*)d_in[2];
    const float* We2 = (const float*)d_in[3];
    const float* be2 = (const float*)d_in[4];
    const float* We3 = (const float*)d_in[5];
    const float* be3 = (const float*)d_in[6];
    const float* emb = (const float*)d_in[7];
    const float* Wd1 = (const float*)d_in[8];
    const float* bd1 = (const float*)d_in[9];
    const float* Wd2 = (const float*)d_in[10];
    const float* bd2 = (const float*)d_in[11];
    const float* Wd3 = (const float*)d_in[12];
    const float* bd3 = (const float*)d_in[13];
    float* out = (float*)d_out;

    // ws layout (floats): dec_out[65536] | W2T[65536] | W1T[16384] | W3T[16384] | en[1024+pad]
    float* ws      = (float*)d_ws;
    float* dec_out = ws;
    float* W2T     = ws + 65536;
    float* W1T     = ws + 131072;
    float* W3T     = ws + 147456;
    float* en      = ws + 163840;   // + pad absorbs fold prefetch overrun

    prep_transpose<<<384, 256, 0, stream>>>(We1, We2, We3, W1T, W2T, W3T);
    prep_decoder<<<256, 256, 0, stream>>>(emb, Wd1, bd1, Wd2, bd2, Wd3, bd3, dec_out, en);
    vqvae_main<<<NROWS / 32, 256, 0, stream>>>(x, be1, be2, be3, W1T, W2T, W3T, emb, en,
                                               dec_out, out);
}